// Round 1
// baseline (933.577 us; speedup 1.0000x reference)
//
#include <hip/hip_runtime.h>

#define N_NODES 100000
#define N_EDGES 1280000
#define D 64

// ---- degree: deg[n] = #edges with dst==n --------------------------------
__global__ __launch_bounds__(256) void deg_kernel(const int* __restrict__ dst,
                                                  float* __restrict__ deg) {
    int e = blockIdx.x * 256 + threadIdx.x;
    if (e < N_EDGES) atomicAdd(&deg[dst[e]], 1.0f);
}

// ---- scatter-add: agg[dst] += feat[src], one 64-lane group per edge -----
__global__ __launch_bounds__(256) void scatter_kernel(const int* __restrict__ src,
                                                      const int* __restrict__ dst,
                                                      const float* __restrict__ feat,
                                                      float* __restrict__ agg) {
    int t = blockIdx.x * 256 + threadIdx.x;
    int e = t >> 6;          // wave-uniform: all 64 lanes share one edge
    int d = t & 63;
    if (e >= N_EDGES) return;
    int s  = src[e];
    int dd = dst[e];
    atomicAdd(&agg[dd * D + d], feat[s * D + d]);
}

// ---- dense: h = relu((agg/deg) @ Wl^T + bl + xin @ Wr^T); optional head -
template <bool HEAD>
__global__ __launch_bounds__(256) void dense_kernel(
    const float* __restrict__ agg, const float* __restrict__ deg,
    const float* __restrict__ xin,
    const float* __restrict__ Wl, const float* __restrict__ bl,
    const float* __restrict__ Wr,
    float* __restrict__ hout,
    const float* __restrict__ Wh, const float* __restrict__ bh,
    float* __restrict__ out)
{
    int n = blockIdx.x * 256 + threadIdx.x;
    if (n >= N_NODES) return;
    float inv = 1.0f / fmaxf(deg[n], 1.0f);

    float acc[D];
#pragma unroll
    for (int j = 0; j < D; ++j) acc[j] = bl[j];

    const float4* a4 = (const float4*)(agg + (size_t)n * D);
    const float4* x4 = (const float4*)(xin + (size_t)n * D);

    for (int kc = 0; kc < D / 4; ++kc) {
        float4 av = a4[kc];
        float4 xv = x4[kc];
        av.x *= inv; av.y *= inv; av.z *= inv; av.w *= inv;
        // Weight indices are lane-uniform -> s_load + SGPR-operand FMAs
#pragma unroll
        for (int j = 0; j < D; ++j) {
            const float* wl = Wl + j * D + kc * 4;
            const float* wr = Wr + j * D + kc * 4;
            acc[j] += av.x * wl[0] + av.y * wl[1] + av.z * wl[2] + av.w * wl[3];
            acc[j] += xv.x * wr[0] + xv.y * wr[1] + xv.z * wr[2] + xv.w * wr[3];
        }
    }

    if (HEAD) {
        float o = bh[0];
#pragma unroll
        for (int j = 0; j < D; ++j) {
            float v = fmaxf(acc[j], 0.0f);
            acc[j] = v;
            o += v * Wh[j];
        }
        out[n] = o;
    } else {
#pragma unroll
        for (int j = 0; j < D; ++j) acc[j] = fmaxf(acc[j], 0.0f);
    }

    float4* h4 = (float4*)(hout + (size_t)n * D);
#pragma unroll
    for (int kc = 0; kc < D / 4; ++kc)
        h4[kc] = make_float4(acc[kc * 4 + 0], acc[kc * 4 + 1],
                             acc[kc * 4 + 2], acc[kc * 4 + 3]);
}

extern "C" void kernel_launch(void* const* d_in, const int* in_sizes, int n_in,
                              void* d_out, int out_size, void* d_ws, size_t ws_size,
                              hipStream_t stream) {
    const float* x   = (const float*)d_in[0];
    const int*   ei  = (const int*)d_in[1];
    const int*   src = ei;
    const int*   dst = ei + N_EDGES;
    const float* W1l = (const float*)d_in[2];
    const float* W1r = (const float*)d_in[3];
    const float* b1  = (const float*)d_in[4];
    const float* W2l = (const float*)d_in[5];
    const float* W2r = (const float*)d_in[6];
    const float* b2  = (const float*)d_in[7];
    const float* Wh  = (const float*)d_in[8];
    const float* bh  = (const float*)d_in[9];

    float* out   = (float*)d_out;        // [N]
    float* h_out = out + N_NODES;        // [N,64]: h1 staging, then final h2

    float* wsf = (float*)d_ws;
    float* deg = wsf;                    // N floats (padded stride 102400)
    float* agg = wsf + 102400;           // N*64 floats

    const int DEG_BLOCKS     = (N_EDGES + 255) / 256;
    const int SCATTER_BLOCKS = (N_EDGES * 64) / 256;   // 320000
    const int DENSE_BLOCKS   = (N_NODES + 255) / 256;

    // zero deg + agg (ws is poisoned 0xAA each call)
    hipMemsetAsync(d_ws, 0, (size_t)(102400 + (size_t)N_NODES * D) * sizeof(float), stream);

    deg_kernel<<<DEG_BLOCKS, 256, 0, stream>>>(dst, deg);

    // ---- layer 1 ----
    scatter_kernel<<<SCATTER_BLOCKS, 256, 0, stream>>>(src, dst, x, agg);
    dense_kernel<false><<<DENSE_BLOCKS, 256, 0, stream>>>(
        agg, deg, x, W1l, b1, W1r, h_out, nullptr, nullptr, nullptr);

    // ---- layer 2 ----
    hipMemsetAsync(agg, 0, (size_t)N_NODES * D * sizeof(float), stream);
    scatter_kernel<<<SCATTER_BLOCKS, 256, 0, stream>>>(src, dst, h_out, agg);
    dense_kernel<true><<<DENSE_BLOCKS, 256, 0, stream>>>(
        agg, deg, h_out, W2l, b2, W2r, h_out, Wh, bh, out);
}

// Round 2
// 522.356 us; speedup vs baseline: 1.7872x; 1.7872x over previous
//
#include <hip/hip_runtime.h>

#define N_NODES 100000
#define N_EDGES 1280000
#define D 64
#define NPAD 102400   // padded N for ws layout

// ---------------- ws layout (in 4-byte units) ----------------
// hist      [0        .. 102400)
// cursor    [102400   .. 204800)
// row_start [204800   .. 307200)   (N+1 used)
// bsum      [307200   .. 308224)
// bscan     [308224   .. 309248)
// csr_src   [309248   .. 1589248)
// mean      [1589248  .. 7989248)  (~32 MB total)

// ---- histogram of dst --------------------------------------------------
__global__ __launch_bounds__(256) void hist_kernel(const int* __restrict__ dst,
                                                   int* __restrict__ hist) {
    int e = blockIdx.x * 256 + threadIdx.x;
    if (e < N_EDGES) atomicAdd(&hist[dst[e]], 1);
}

// ---- scan pass 1: per-block exclusive scan + block sums ----------------
__global__ __launch_bounds__(256) void scan1_kernel(const int* __restrict__ hist,
                                                    int* __restrict__ rs,
                                                    int* __restrict__ bsum) {
    __shared__ int tmp[256];
    int tid = threadIdx.x;
    int i = blockIdx.x * 256 + tid;
    int v = (i < N_NODES) ? hist[i] : 0;
    tmp[tid] = v;
    __syncthreads();
    for (int off = 1; off < 256; off <<= 1) {
        int t = (tid >= off) ? tmp[tid - off] : 0;
        __syncthreads();
        tmp[tid] += t;
        __syncthreads();
    }
    if (i < N_NODES) rs[i] = tmp[tid] - v;          // exclusive within block
    if (tid == 255) bsum[blockIdx.x] = tmp[255];    // block total
}

// ---- scan pass 2: exclusive scan of block sums (single block) ----------
__global__ __launch_bounds__(512) void scan2_kernel(const int* __restrict__ bsum,
                                                    int* __restrict__ bscan,
                                                    int nblocks) {
    __shared__ int tmp[512];
    int tid = threadIdx.x;
    int v = (tid < nblocks) ? bsum[tid] : 0;
    tmp[tid] = v;
    __syncthreads();
    for (int off = 1; off < 512; off <<= 1) {
        int t = (tid >= off) ? tmp[tid - off] : 0;
        __syncthreads();
        tmp[tid] += t;
        __syncthreads();
    }
    if (tid < nblocks) bscan[tid] = tmp[tid] - v;
}

// ---- scan pass 3: add block offsets ------------------------------------
__global__ __launch_bounds__(256) void scan3_kernel(int* __restrict__ rs,
                                                    const int* __restrict__ bscan) {
    int i = blockIdx.x * 256 + threadIdx.x;
    if (i < N_NODES) rs[i] += bscan[i >> 8];
    if (i == 0) rs[N_NODES] = N_EDGES;
}

// ---- fill CSR: csr_src grouped by dst ----------------------------------
__global__ __launch_bounds__(256) void fill_kernel(const int* __restrict__ src,
                                                   const int* __restrict__ dst,
                                                   const int* __restrict__ rs,
                                                   int* __restrict__ cursor,
                                                   int* __restrict__ csr_src) {
    int e = blockIdx.x * 256 + threadIdx.x;
    if (e >= N_EDGES) return;
    int d = dst[e];
    int pos = atomicAdd(&cursor[d], 1);
    csr_src[rs[d] + pos] = src[e];
}

// ---- gather-mean: 16 lanes per node, float4 per lane -------------------
__global__ __launch_bounds__(256) void gather_kernel(const int* __restrict__ csr_src,
                                                     const int* __restrict__ rs,
                                                     const float* __restrict__ feat,
                                                     float* __restrict__ mean_out) {
    int t = blockIdx.x * 256 + threadIdx.x;
    int n = t >> 4;
    int l = t & 15;
    if (n >= N_NODES) return;
    int beg = rs[n], end = rs[n + 1];
    const float4* f4 = (const float4*)feat;
    float4 acc = make_float4(0.f, 0.f, 0.f, 0.f);
    for (int base = beg; base < end; base += 16) {
        int cnt = end - base;
        if (cnt > 16) cnt = 16;
        int id = 0;
        if (base + l < end) id = csr_src[base + l];   // 16 edge ids per group
        for (int i = 0; i < cnt; ++i) {
            int sidx = __shfl(id, i, 16);             // broadcast within 16-group
            float4 v = f4[sidx * 16 + l];             // 256 B per node-group
            acc.x += v.x; acc.y += v.y; acc.z += v.z; acc.w += v.w;
        }
    }
    float inv = 1.0f / fmaxf((float)(end - beg), 1.0f);
    acc.x *= inv; acc.y *= inv; acc.z *= inv; acc.w *= inv;
    ((float4*)mean_out)[n * 16 + l] = acc;
}

// ---- dense: h = relu(mean @ Wl^T + bl + xin @ Wr^T); optional head -----
template <bool HEAD>
__global__ __launch_bounds__(256) void dense_kernel(
    const float* __restrict__ mean, const float* __restrict__ xin,
    const float* __restrict__ Wl, const float* __restrict__ bl,
    const float* __restrict__ Wr,
    float* __restrict__ hout,
    const float* __restrict__ Wh, const float* __restrict__ bh,
    float* __restrict__ out)
{
    int n = blockIdx.x * 256 + threadIdx.x;
    if (n >= N_NODES) return;

    float acc[D];
#pragma unroll
    for (int j = 0; j < D; ++j) acc[j] = bl[j];

    const float4* a4 = (const float4*)(mean + (size_t)n * D);
    const float4* x4 = (const float4*)(xin + (size_t)n * D);

    for (int kc = 0; kc < D / 4; ++kc) {
        float4 av = a4[kc];
        float4 xv = x4[kc];
#pragma unroll
        for (int j = 0; j < D; ++j) {
            const float* wl = Wl + j * D + kc * 4;
            const float* wr = Wr + j * D + kc * 4;
            acc[j] += av.x * wl[0] + av.y * wl[1] + av.z * wl[2] + av.w * wl[3];
            acc[j] += xv.x * wr[0] + xv.y * wr[1] + xv.z * wr[2] + xv.w * wr[3];
        }
    }

    if (HEAD) {
        float o = bh[0];
#pragma unroll
        for (int j = 0; j < D; ++j) {
            float v = fmaxf(acc[j], 0.0f);
            acc[j] = v;
            o += v * Wh[j];
        }
        out[n] = o;
    } else {
#pragma unroll
        for (int j = 0; j < D; ++j) acc[j] = fmaxf(acc[j], 0.0f);
    }

    float4* h4 = (float4*)(hout + (size_t)n * D);
#pragma unroll
    for (int kc = 0; kc < D / 4; ++kc)
        h4[kc] = make_float4(acc[kc * 4 + 0], acc[kc * 4 + 1],
                             acc[kc * 4 + 2], acc[kc * 4 + 3]);
}

extern "C" void kernel_launch(void* const* d_in, const int* in_sizes, int n_in,
                              void* d_out, int out_size, void* d_ws, size_t ws_size,
                              hipStream_t stream) {
    const float* x   = (const float*)d_in[0];
    const int*   ei  = (const int*)d_in[1];
    const int*   src = ei;
    const int*   dst = ei + N_EDGES;
    const float* W1l = (const float*)d_in[2];
    const float* W1r = (const float*)d_in[3];
    const float* b1  = (const float*)d_in[4];
    const float* W2l = (const float*)d_in[5];
    const float* W2r = (const float*)d_in[6];
    const float* b2  = (const float*)d_in[7];
    const float* Wh  = (const float*)d_in[8];
    const float* bh  = (const float*)d_in[9];

    float* out   = (float*)d_out;        // [N]
    float* h_out = out + N_NODES;        // [N,64]

    int* wsi      = (int*)d_ws;
    int* hist     = wsi;
    int* cursor   = wsi + NPAD;
    int* rs       = wsi + 2 * NPAD;      // row_start, N+1 used
    int* bsum     = wsi + 3 * NPAD;
    int* bscan    = wsi + 3 * NPAD + 1024;
    int* csr_src  = wsi + 3 * NPAD + 2048;
    float* mean   = (float*)(csr_src + N_EDGES);

    const int EB  = (N_EDGES + 255) / 256;       // 5000
    const int NB  = (N_NODES + 255) / 256;       // 391
    const int GB  = (N_NODES * 16 + 255) / 256;  // 6250

    // zero hist + cursor (ws is poisoned 0xAA each call)
    hipMemsetAsync(d_ws, 0, (size_t)(2 * NPAD) * sizeof(int), stream);

    // ---- CSR build ----
    hist_kernel <<<EB, 256, 0, stream>>>(dst, hist);
    scan1_kernel<<<NB, 256, 0, stream>>>(hist, rs, bsum);
    scan2_kernel<<<1, 512, 0, stream>>>(bsum, bscan, NB);
    scan3_kernel<<<NB, 256, 0, stream>>>(rs, bscan);
    fill_kernel <<<EB, 256, 0, stream>>>(src, dst, rs, cursor, csr_src);

    // ---- layer 1 ----
    gather_kernel<<<GB, 256, 0, stream>>>(csr_src, rs, x, mean);
    dense_kernel<false><<<NB, 256, 0, stream>>>(
        mean, x, W1l, b1, W1r, h_out, nullptr, nullptr, nullptr);

    // ---- layer 2 ----
    gather_kernel<<<GB, 256, 0, stream>>>(csr_src, rs, h_out, mean);
    dense_kernel<true><<<NB, 256, 0, stream>>>(
        mean, h_out, W2l, b2, W2r, h_out, Wh, bh, out);
}

// Round 3
// 432.680 us; speedup vs baseline: 2.1577x; 1.2073x over previous
//
#include <hip/hip_runtime.h>

#define N_NODES 100000
#define N_EDGES 1280000
#define D 64
#define NPAD 102400   // padded N for ws layout

// ---- histogram of dst --------------------------------------------------
__global__ __launch_bounds__(256) void hist_kernel(const int* __restrict__ dst,
                                                   int* __restrict__ hist) {
    int e = blockIdx.x * 256 + threadIdx.x;
    if (e < N_EDGES) atomicAdd(&hist[dst[e]], 1);
}

// ---- scan pass 1: per-block exclusive scan + block sums ----------------
__global__ __launch_bounds__(256) void scan1_kernel(const int* __restrict__ hist,
                                                    int* __restrict__ rs,
                                                    int* __restrict__ bsum) {
    __shared__ int tmp[256];
    int tid = threadIdx.x;
    int i = blockIdx.x * 256 + tid;
    int v = (i < N_NODES) ? hist[i] : 0;
    tmp[tid] = v;
    __syncthreads();
    for (int off = 1; off < 256; off <<= 1) {
        int t = (tid >= off) ? tmp[tid - off] : 0;
        __syncthreads();
        tmp[tid] += t;
        __syncthreads();
    }
    if (i < N_NODES) rs[i] = tmp[tid] - v;
    if (tid == 255) bsum[blockIdx.x] = tmp[255];
}

// ---- scan pass 2: exclusive scan of block sums (single block) ----------
__global__ __launch_bounds__(512) void scan2_kernel(const int* __restrict__ bsum,
                                                    int* __restrict__ bscan,
                                                    int nblocks) {
    __shared__ int tmp[512];
    int tid = threadIdx.x;
    int v = (tid < nblocks) ? bsum[tid] : 0;
    tmp[tid] = v;
    __syncthreads();
    for (int off = 1; off < 512; off <<= 1) {
        int t = (tid >= off) ? tmp[tid - off] : 0;
        __syncthreads();
        tmp[tid] += t;
        __syncthreads();
    }
    if (tid < nblocks) bscan[tid] = tmp[tid] - v;
}

// ---- scan pass 3: add block offsets ------------------------------------
__global__ __launch_bounds__(256) void scan3_kernel(int* __restrict__ rs,
                                                    const int* __restrict__ bscan) {
    int i = blockIdx.x * 256 + threadIdx.x;
    if (i < N_NODES) rs[i] += bscan[i >> 8];
    if (i == 0) rs[N_NODES] = N_EDGES;
}

// ---- fill CSR: csr_src grouped by dst ----------------------------------
__global__ __launch_bounds__(256) void fill_kernel(const int* __restrict__ src,
                                                   const int* __restrict__ dst,
                                                   const int* __restrict__ rs,
                                                   int* __restrict__ cursor,
                                                   int* __restrict__ csr_src) {
    int e = blockIdx.x * 256 + threadIdx.x;
    if (e >= N_EDGES) return;
    int d = dst[e];
    int pos = atomicAdd(&cursor[d], 1);
    csr_src[rs[d] + pos] = src[e];
}

// ---- gather-mean: 16 lanes per node, float4 per lane -------------------
__global__ __launch_bounds__(256) void gather_kernel(const int* __restrict__ csr_src,
                                                     const int* __restrict__ rs,
                                                     const float* __restrict__ feat,
                                                     float* __restrict__ mean_out) {
    int t = blockIdx.x * 256 + threadIdx.x;
    int n = t >> 4;
    int l = t & 15;
    if (n >= N_NODES) return;
    int beg = rs[n], end = rs[n + 1];
    const float4* f4 = (const float4*)feat;
    float4 acc = make_float4(0.f, 0.f, 0.f, 0.f);
    for (int base = beg; base < end; base += 16) {
        int cnt = end - base;
        if (cnt > 16) cnt = 16;
        int id = 0;
        if (base + l < end) id = csr_src[base + l];
        for (int i = 0; i < cnt; ++i) {
            int sidx = __shfl(id, i, 16);
            float4 v = f4[sidx * 16 + l];
            acc.x += v.x; acc.y += v.y; acc.z += v.z; acc.w += v.w;
        }
    }
    float inv = 1.0f / fmaxf((float)(end - beg), 1.0f);
    acc.x *= inv; acc.y *= inv; acc.z *= inv; acc.w *= inv;
    ((float4*)mean_out)[n * 16 + l] = acc;
}

// ---- dense v2: LDS-tiled, 64 nodes/block, wave w -> output cols [16w,16w+16)
// h = relu(mean @ Wl^T + bl + xin @ Wr^T); optional fused head.
// In-place safe: each block stages exactly the 64 rows it later writes.
template <bool HEAD>
__global__ __launch_bounds__(256) void dense_kernel(
    const float* __restrict__ mean, const float* __restrict__ xin,
    const float* __restrict__ Wl, const float* __restrict__ bl,
    const float* __restrict__ Wr,
    float* __restrict__ hout,
    const float* __restrict__ Wh, const float* __restrict__ bh,
    float* __restrict__ out)
{
    __shared__ float sm[64 * 65];
    __shared__ float sx[64 * 65];
    __shared__ float spart[256];

    const int tid = threadIdx.x;
    const int n0  = blockIdx.x * 64;

    // ---- stage 64 rows of mean and xin into LDS (coalesced float4) ----
#pragma unroll
    for (int i = 0; i < 4; ++i) {
        int f4  = tid + 256 * i;          // float4 index within 64x64 tile
        int row = f4 >> 4;
        int c4  = f4 & 15;
        int n   = n0 + row;
        float4 mv = make_float4(0.f, 0.f, 0.f, 0.f);
        float4 xv = make_float4(0.f, 0.f, 0.f, 0.f);
        if (n < N_NODES) {
            mv = ((const float4*)mean)[(size_t)n * 16 + c4];
            xv = ((const float4*)xin )[(size_t)n * 16 + c4];
        }
        int b = row * 65 + c4 * 4;
        sm[b + 0] = mv.x; sm[b + 1] = mv.y; sm[b + 2] = mv.z; sm[b + 3] = mv.w;
        sx[b + 0] = xv.x; sx[b + 1] = xv.y; sx[b + 2] = xv.z; sx[b + 3] = xv.w;
    }
    __syncthreads();

    const int lane = tid & 63;
    // wave-uniform output-column base -> forces s_load for weights
    const int j0 = __builtin_amdgcn_readfirstlane((tid >> 6) * 16);

    float acc[16];
#pragma unroll
    for (int j = 0; j < 16; ++j) acc[j] = bl[j0 + j];

#pragma unroll 4
    for (int k = 0; k < D; ++k) {
        float am = sm[lane * 65 + k];
        float xv = sx[lane * 65 + k];
#pragma unroll
        for (int j = 0; j < 16; ++j) {
            acc[j] += am * Wl[(j0 + j) * D + k] + xv * Wr[(j0 + j) * D + k];
        }
    }

    // relu
#pragma unroll
    for (int j = 0; j < 16; ++j) acc[j] = fmaxf(acc[j], 0.0f);

    if (HEAD) {
        float p = 0.0f;
#pragma unroll
        for (int j = 0; j < 16; ++j) p += acc[j] * Wh[j0 + j];
        spart[tid] = p;
    }

    __syncthreads();   // everyone done reading sm/sx; safe to reuse sm

    // ---- write h back through LDS for coalesced global stores ----
#pragma unroll
    for (int j = 0; j < 16; ++j) sm[lane * 65 + j0 + j] = acc[j];
    __syncthreads();

#pragma unroll
    for (int i = 0; i < 4; ++i) {
        int f4  = tid + 256 * i;
        int row = f4 >> 4;
        int c4  = f4 & 15;
        int n   = n0 + row;
        if (n < N_NODES) {
            int b = row * 65 + c4 * 4;
            ((float4*)hout)[(size_t)n * 16 + c4] =
                make_float4(sm[b + 0], sm[b + 1], sm[b + 2], sm[b + 3]);
        }
        if (HEAD && i == 0 && tid < 64) {
            int n2 = n0 + tid;
            if (n2 < N_NODES)
                out[n2] = bh[0] + spart[tid] + spart[64 + tid] +
                          spart[128 + tid] + spart[192 + tid];
        }
    }
}

extern "C" void kernel_launch(void* const* d_in, const int* in_sizes, int n_in,
                              void* d_out, int out_size, void* d_ws, size_t ws_size,
                              hipStream_t stream) {
    const float* x   = (const float*)d_in[0];
    const int*   ei  = (const int*)d_in[1];
    const int*   src = ei;
    const int*   dst = ei + N_EDGES;
    const float* W1l = (const float*)d_in[2];
    const float* W1r = (const float*)d_in[3];
    const float* b1  = (const float*)d_in[4];
    const float* W2l = (const float*)d_in[5];
    const float* W2r = (const float*)d_in[6];
    const float* b2  = (const float*)d_in[7];
    const float* Wh  = (const float*)d_in[8];
    const float* bh  = (const float*)d_in[9];

    float* out   = (float*)d_out;        // [N]
    float* h_out = out + N_NODES;        // [N,64]

    int* wsi      = (int*)d_ws;
    int* hist     = wsi;
    int* cursor   = wsi + NPAD;
    int* rs       = wsi + 2 * NPAD;      // row_start, N+1 used
    int* bsum     = wsi + 3 * NPAD;
    int* bscan    = wsi + 3 * NPAD + 1024;
    int* csr_src  = wsi + 3 * NPAD + 2048;
    float* mean   = (float*)(csr_src + N_EDGES);

    const int EB  = (N_EDGES + 255) / 256;       // 5000
    const int NB  = (N_NODES + 255) / 256;       // 391
    const int GB  = (N_NODES * 16 + 255) / 256;  // 6250
    const int DB  = (N_NODES + 63) / 64;         // 1563

    hipMemsetAsync(d_ws, 0, (size_t)(2 * NPAD) * sizeof(int), stream);

    // ---- CSR build ----
    hist_kernel <<<EB, 256, 0, stream>>>(dst, hist);
    scan1_kernel<<<NB, 256, 0, stream>>>(hist, rs, bsum);
    scan2_kernel<<<1, 512, 0, stream>>>(bsum, bscan, NB);
    scan3_kernel<<<NB, 256, 0, stream>>>(rs, bscan);
    fill_kernel <<<EB, 256, 0, stream>>>(src, dst, rs, cursor, csr_src);

    // ---- layer 1 ----
    gather_kernel<<<GB, 256, 0, stream>>>(csr_src, rs, x, mean);
    dense_kernel<false><<<DB, 256, 0, stream>>>(
        mean, x, W1l, b1, W1r, h_out, nullptr, nullptr, nullptr);

    // ---- layer 2 ----
    gather_kernel<<<GB, 256, 0, stream>>>(csr_src, rs, h_out, mean);
    dense_kernel<true><<<DB, 256, 0, stream>>>(
        mean, h_out, W2l, b2, W2r, h_out, Wh, bh, out);
}

// Round 4
// 383.174 us; speedup vs baseline: 2.4364x; 1.1292x over previous
//
#include <hip/hip_runtime.h>

#define N_NODES 100000
#define N_EDGES 1280000
#define D 64
#define NPAD 102400   // padded N for ws layout

// ---------------- ws layout (in 4-byte units) ----------------
// hist     [0            .. NPAD)
// rs       [NPAD         .. 2*NPAD)        (N+1 used)
// bsum     [2*NPAD       .. 2*NPAD+1024)
// bscan    [2*NPAD+1024  .. 2*NPAD+2048)
// csr_src  [2*NPAD+2048  .. +N_EDGES)
// mean/pos [..           .. +N*64)   pos[e] lives here until gather1 overwrites
// total = 7,886,848 ints = 31.5 MB

// ---- histogram of dst + per-edge rank (atomicAdd returns old) ----------
__global__ __launch_bounds__(256) void hist_kernel(const int* __restrict__ dst,
                                                   int* __restrict__ hist,
                                                   int* __restrict__ pos) {
    int e = blockIdx.x * 256 + threadIdx.x;
    if (e < N_EDGES) pos[e] = atomicAdd(&hist[dst[e]], 1);
}

// ---- scan pass 1: per-block exclusive scan + block sums ----------------
__global__ __launch_bounds__(256) void scan1_kernel(const int* __restrict__ hist,
                                                    int* __restrict__ rs,
                                                    int* __restrict__ bsum) {
    __shared__ int tmp[256];
    int tid = threadIdx.x;
    int i = blockIdx.x * 256 + tid;
    int v = (i < N_NODES) ? hist[i] : 0;
    tmp[tid] = v;
    __syncthreads();
    for (int off = 1; off < 256; off <<= 1) {
        int t = (tid >= off) ? tmp[tid - off] : 0;
        __syncthreads();
        tmp[tid] += t;
        __syncthreads();
    }
    if (i < N_NODES) rs[i] = tmp[tid] - v;
    if (tid == 255) bsum[blockIdx.x] = tmp[255];
}

// ---- scan pass 2: exclusive scan of block sums (single block) ----------
__global__ __launch_bounds__(512) void scan2_kernel(const int* __restrict__ bsum,
                                                    int* __restrict__ bscan,
                                                    int nblocks) {
    __shared__ int tmp[512];
    int tid = threadIdx.x;
    int v = (tid < nblocks) ? bsum[tid] : 0;
    tmp[tid] = v;
    __syncthreads();
    for (int off = 1; off < 512; off <<= 1) {
        int t = (tid >= off) ? tmp[tid - off] : 0;
        __syncthreads();
        tmp[tid] += t;
        __syncthreads();
    }
    if (tid < nblocks) bscan[tid] = tmp[tid] - v;
}

// ---- scan pass 3: add block offsets ------------------------------------
__global__ __launch_bounds__(256) void scan3_kernel(int* __restrict__ rs,
                                                    const int* __restrict__ bscan) {
    int i = blockIdx.x * 256 + threadIdx.x;
    if (i < N_NODES) rs[i] += bscan[i >> 8];
    if (i == 0) rs[N_NODES] = N_EDGES;
}

// ---- fill CSR (atomic-free): rank precomputed in hist ------------------
__global__ __launch_bounds__(256) void fill_kernel(const int* __restrict__ src,
                                                   const int* __restrict__ dst,
                                                   const int* __restrict__ rs,
                                                   const int* __restrict__ pos,
                                                   int* __restrict__ csr_src) {
    int e = blockIdx.x * 256 + threadIdx.x;
    if (e >= N_EDGES) return;
    csr_src[rs[dst[e]] + pos[e]] = src[e];
}

// ---- gather-mean: 16 lanes/node, float4/lane, 4-way unrolled MLP -------
__global__ __launch_bounds__(256) void gather_kernel(const int* __restrict__ csr_src,
                                                     const int* __restrict__ rs,
                                                     const float* __restrict__ feat,
                                                     float* __restrict__ mean_out) {
    int t = blockIdx.x * 256 + threadIdx.x;
    int n = t >> 4;
    int l = t & 15;
    if (n >= N_NODES) return;
    int beg = rs[n], end = rs[n + 1];
    const float4* f4 = (const float4*)feat;
    float4 acc = make_float4(0.f, 0.f, 0.f, 0.f);
    for (int base = beg; base < end; base += 16) {
        int rem = end - base;
        if (rem > 16) rem = 16;
        int id = 0;
        if (base + l < end) id = csr_src[base + l];   // 16 ids, coalesced
        int i = 0;
        for (; i + 4 <= rem; i += 4) {                // 4 independent row loads
            int s0 = __shfl(id, i + 0, 16);
            int s1 = __shfl(id, i + 1, 16);
            int s2 = __shfl(id, i + 2, 16);
            int s3 = __shfl(id, i + 3, 16);
            float4 v0 = f4[(size_t)s0 * 16 + l];
            float4 v1 = f4[(size_t)s1 * 16 + l];
            float4 v2 = f4[(size_t)s2 * 16 + l];
            float4 v3 = f4[(size_t)s3 * 16 + l];
            acc.x += (v0.x + v1.x) + (v2.x + v3.x);
            acc.y += (v0.y + v1.y) + (v2.y + v3.y);
            acc.z += (v0.z + v1.z) + (v2.z + v3.z);
            acc.w += (v0.w + v1.w) + (v2.w + v3.w);
        }
        for (; i < rem; ++i) {
            int s = __shfl(id, i, 16);
            float4 v = f4[(size_t)s * 16 + l];
            acc.x += v.x; acc.y += v.y; acc.z += v.z; acc.w += v.w;
        }
    }
    float inv = 1.0f / fmaxf((float)(end - beg), 1.0f);
    acc.x *= inv; acc.y *= inv; acc.z *= inv; acc.w *= inv;
    ((float4*)mean_out)[n * 16 + l] = acc;
}

// ---- dense: LDS-tiled, 64 nodes/block, wave w -> output cols [16w,16w+16)
template <bool HEAD>
__global__ __launch_bounds__(256) void dense_kernel(
    const float* __restrict__ mean, const float* __restrict__ xin,
    const float* __restrict__ Wl, const float* __restrict__ bl,
    const float* __restrict__ Wr,
    float* __restrict__ hout,
    const float* __restrict__ Wh, const float* __restrict__ bh,
    float* __restrict__ out)
{
    __shared__ float sm[64 * 65];
    __shared__ float sx[64 * 65];
    __shared__ float spart[256];

    const int tid = threadIdx.x;
    const int n0  = blockIdx.x * 64;

#pragma unroll
    for (int i = 0; i < 4; ++i) {
        int f4  = tid + 256 * i;
        int row = f4 >> 4;
        int c4  = f4 & 15;
        int n   = n0 + row;
        float4 mv = make_float4(0.f, 0.f, 0.f, 0.f);
        float4 xv = make_float4(0.f, 0.f, 0.f, 0.f);
        if (n < N_NODES) {
            mv = ((const float4*)mean)[(size_t)n * 16 + c4];
            xv = ((const float4*)xin )[(size_t)n * 16 + c4];
        }
        int b = row * 65 + c4 * 4;
        sm[b + 0] = mv.x; sm[b + 1] = mv.y; sm[b + 2] = mv.z; sm[b + 3] = mv.w;
        sx[b + 0] = xv.x; sx[b + 1] = xv.y; sx[b + 2] = xv.z; sx[b + 3] = xv.w;
    }
    __syncthreads();

    const int lane = tid & 63;
    const int j0 = __builtin_amdgcn_readfirstlane((tid >> 6) * 16);

    float acc[16];
#pragma unroll
    for (int j = 0; j < 16; ++j) acc[j] = bl[j0 + j];

#pragma unroll 4
    for (int k = 0; k < D; ++k) {
        float am = sm[lane * 65 + k];
        float xv = sx[lane * 65 + k];
#pragma unroll
        for (int j = 0; j < 16; ++j) {
            acc[j] += am * Wl[(j0 + j) * D + k] + xv * Wr[(j0 + j) * D + k];
        }
    }

#pragma unroll
    for (int j = 0; j < 16; ++j) acc[j] = fmaxf(acc[j], 0.0f);

    if (HEAD) {
        float p = 0.0f;
#pragma unroll
        for (int j = 0; j < 16; ++j) p += acc[j] * Wh[j0 + j];
        spart[tid] = p;
    }

    __syncthreads();

#pragma unroll
    for (int j = 0; j < 16; ++j) sm[lane * 65 + j0 + j] = acc[j];
    __syncthreads();

#pragma unroll
    for (int i = 0; i < 4; ++i) {
        int f4  = tid + 256 * i;
        int row = f4 >> 4;
        int c4  = f4 & 15;
        int n   = n0 + row;
        if (n < N_NODES) {
            int b = row * 65 + c4 * 4;
            ((float4*)hout)[(size_t)n * 16 + c4] =
                make_float4(sm[b + 0], sm[b + 1], sm[b + 2], sm[b + 3]);
        }
        if (HEAD && i == 0 && tid < 64) {
            int n2 = n0 + tid;
            if (n2 < N_NODES)
                out[n2] = bh[0] + spart[tid] + spart[64 + tid] +
                          spart[128 + tid] + spart[192 + tid];
        }
    }
}

extern "C" void kernel_launch(void* const* d_in, const int* in_sizes, int n_in,
                              void* d_out, int out_size, void* d_ws, size_t ws_size,
                              hipStream_t stream) {
    const float* x   = (const float*)d_in[0];
    const int*   ei  = (const int*)d_in[1];
    const int*   src = ei;
    const int*   dst = ei + N_EDGES;
    const float* W1l = (const float*)d_in[2];
    const float* W1r = (const float*)d_in[3];
    const float* b1  = (const float*)d_in[4];
    const float* W2l = (const float*)d_in[5];
    const float* W2r = (const float*)d_in[6];
    const float* b2  = (const float*)d_in[7];
    const float* Wh  = (const float*)d_in[8];
    const float* bh  = (const float*)d_in[9];

    float* out   = (float*)d_out;        // [N]
    float* h_out = out + N_NODES;        // [N,64]

    int* wsi      = (int*)d_ws;
    int* hist     = wsi;
    int* rs       = wsi + NPAD;          // N+1 used
    int* bsum     = wsi + 2 * NPAD;
    int* bscan    = wsi + 2 * NPAD + 1024;
    int* csr_src  = wsi + 2 * NPAD + 2048;
    float* mean   = (float*)(csr_src + N_EDGES);
    int* pos      = (int*)mean;          // pos[e] dies before gather1 writes mean

    const int EB  = (N_EDGES + 255) / 256;       // 5000
    const int NB  = (N_NODES + 255) / 256;       // 391
    const int GB  = (N_NODES * 16 + 255) / 256;  // 6250
    const int DB  = (N_NODES + 63) / 64;         // 1563

    // zero hist only (ws is poisoned 0xAA each call)
    hipMemsetAsync(d_ws, 0, (size_t)NPAD * sizeof(int), stream);

    // ---- CSR build ----
    hist_kernel <<<EB, 256, 0, stream>>>(dst, hist, pos);
    scan1_kernel<<<NB, 256, 0, stream>>>(hist, rs, bsum);
    scan2_kernel<<<1, 512, 0, stream>>>(bsum, bscan, NB);
    scan3_kernel<<<NB, 256, 0, stream>>>(rs, bscan);
    fill_kernel <<<EB, 256, 0, stream>>>(src, dst, rs, pos, csr_src);

    // ---- layer 1 ----
    gather_kernel<<<GB, 256, 0, stream>>>(csr_src, rs, x, mean);
    dense_kernel<false><<<DB, 256, 0, stream>>>(
        mean, x, W1l, b1, W1r, h_out, nullptr, nullptr, nullptr);

    // ---- layer 2 ----
    gather_kernel<<<GB, 256, 0, stream>>>(csr_src, rs, h_out, mean);
    dense_kernel<true><<<DB, 256, 0, stream>>>(
        mean, h_out, W2l, b2, W2r, h_out, Wh, bh, out);
}

// Round 5
// 287.419 us; speedup vs baseline: 3.2481x; 1.3332x over previous
//
#include <hip/hip_runtime.h>

#define N_NODES 100000
#define N_EDGES 1280000
#define D 64
#define NPAD 102400   // padded N for ws layout

typedef __attribute__((ext_vector_type(8))) short bf16x8;
typedef __attribute__((ext_vector_type(4))) float f32x4;

__device__ __forceinline__ unsigned short f2bf(float f) {
    union { float f; unsigned u; } c; c.f = f;
    unsigned u = c.u;
    return (unsigned short)((u + 0x7FFF + ((u >> 16) & 1)) >> 16);   // RNE
}
__device__ __forceinline__ float bf2f(unsigned short s) {
    union { unsigned u; float f; } c; c.u = ((unsigned)s) << 16;
    return c.f;
}

// ---- weight convert: 4 matrices of 64x64 fp32 -> bf16 ------------------
__global__ __launch_bounds__(256) void wcvt_kernel(const float* __restrict__ a,
                                                   const float* __restrict__ b,
                                                   const float* __restrict__ c,
                                                   const float* __restrict__ d,
                                                   unsigned short* __restrict__ wb) {
    int i = blockIdx.x * 256 + threadIdx.x;
    if (i >= 4 * 4096) return;
    int m = i >> 12, k = i & 4095;
    const float* s = (m == 0) ? a : (m == 1) ? b : (m == 2) ? c : d;
    wb[i] = f2bf(s[k]);
}

// ---- histogram of dst + per-edge rank (atomicAdd returns old) ----------
__global__ __launch_bounds__(256) void hist_kernel(const int* __restrict__ dst,
                                                   int* __restrict__ hist,
                                                   int* __restrict__ pos) {
    int e = blockIdx.x * 256 + threadIdx.x;
    if (e < N_EDGES) pos[e] = atomicAdd(&hist[dst[e]], 1);
}

// ---- scan pass 1 --------------------------------------------------------
__global__ __launch_bounds__(256) void scan1_kernel(const int* __restrict__ hist,
                                                    int* __restrict__ rs,
                                                    int* __restrict__ bsum) {
    __shared__ int tmp[256];
    int tid = threadIdx.x;
    int i = blockIdx.x * 256 + tid;
    int v = (i < N_NODES) ? hist[i] : 0;
    tmp[tid] = v;
    __syncthreads();
    for (int off = 1; off < 256; off <<= 1) {
        int t = (tid >= off) ? tmp[tid - off] : 0;
        __syncthreads();
        tmp[tid] += t;
        __syncthreads();
    }
    if (i < N_NODES) rs[i] = tmp[tid] - v;
    if (tid == 255) bsum[blockIdx.x] = tmp[255];
}

// ---- scan pass 2 --------------------------------------------------------
__global__ __launch_bounds__(512) void scan2_kernel(const int* __restrict__ bsum,
                                                    int* __restrict__ bscan,
                                                    int nblocks) {
    __shared__ int tmp[512];
    int tid = threadIdx.x;
    int v = (tid < nblocks) ? bsum[tid] : 0;
    tmp[tid] = v;
    __syncthreads();
    for (int off = 1; off < 512; off <<= 1) {
        int t = (tid >= off) ? tmp[tid - off] : 0;
        __syncthreads();
        tmp[tid] += t;
        __syncthreads();
    }
    if (tid < nblocks) bscan[tid] = tmp[tid] - v;
}

// ---- scan pass 3 --------------------------------------------------------
__global__ __launch_bounds__(256) void scan3_kernel(int* __restrict__ rs,
                                                    const int* __restrict__ bscan) {
    int i = blockIdx.x * 256 + threadIdx.x;
    if (i < N_NODES) rs[i] += bscan[i >> 8];
    if (i == 0) rs[N_NODES] = N_EDGES;
}

// ---- fill CSR (atomic-free) --------------------------------------------
__global__ __launch_bounds__(256) void fill_kernel(const int* __restrict__ src,
                                                   const int* __restrict__ dst,
                                                   const int* __restrict__ rs,
                                                   const int* __restrict__ pos,
                                                   int* __restrict__ csr_src) {
    int e = blockIdx.x * 256 + threadIdx.x;
    if (e >= N_EDGES) return;
    csr_src[rs[dst[e]] + pos[e]] = src[e];
}

// ---- gather-mean: 16 lanes/node, 4-way MLP; fp32 or bf16 rows -> bf16 mean
template <bool BF>
__global__ __launch_bounds__(256) void gather_kernel(const int* __restrict__ csr_src,
                                                     const int* __restrict__ rs,
                                                     const void* __restrict__ feat,
                                                     unsigned short* __restrict__ mean_b) {
    int t = blockIdx.x * 256 + threadIdx.x;
    int n = t >> 4;
    int l = t & 15;
    if (n >= N_NODES) return;
    int beg = rs[n], end = rs[n + 1];
    const float4*  ff = (const float4*)feat;
    const ushort4* fb = (const ushort4*)feat;
    float ax = 0.f, ay = 0.f, az = 0.f, aw = 0.f;
    for (int base = beg; base < end; base += 16) {
        int rem = end - base;
        if (rem > 16) rem = 16;
        int id = 0;
        if (base + l < end) id = csr_src[base + l];
        int i = 0;
        for (; i + 4 <= rem; i += 4) {
            int s0 = __shfl(id, i + 0, 16);
            int s1 = __shfl(id, i + 1, 16);
            int s2 = __shfl(id, i + 2, 16);
            int s3 = __shfl(id, i + 3, 16);
            if (BF) {
                ushort4 v0 = fb[(size_t)s0 * 16 + l];
                ushort4 v1 = fb[(size_t)s1 * 16 + l];
                ushort4 v2 = fb[(size_t)s2 * 16 + l];
                ushort4 v3 = fb[(size_t)s3 * 16 + l];
                ax += (bf2f(v0.x) + bf2f(v1.x)) + (bf2f(v2.x) + bf2f(v3.x));
                ay += (bf2f(v0.y) + bf2f(v1.y)) + (bf2f(v2.y) + bf2f(v3.y));
                az += (bf2f(v0.z) + bf2f(v1.z)) + (bf2f(v2.z) + bf2f(v3.z));
                aw += (bf2f(v0.w) + bf2f(v1.w)) + (bf2f(v2.w) + bf2f(v3.w));
            } else {
                float4 v0 = ff[(size_t)s0 * 16 + l];
                float4 v1 = ff[(size_t)s1 * 16 + l];
                float4 v2 = ff[(size_t)s2 * 16 + l];
                float4 v3 = ff[(size_t)s3 * 16 + l];
                ax += (v0.x + v1.x) + (v2.x + v3.x);
                ay += (v0.y + v1.y) + (v2.y + v3.y);
                az += (v0.z + v1.z) + (v2.z + v3.z);
                aw += (v0.w + v1.w) + (v2.w + v3.w);
            }
        }
        for (; i < rem; ++i) {
            int s = __shfl(id, i, 16);
            if (BF) {
                ushort4 v = fb[(size_t)s * 16 + l];
                ax += bf2f(v.x); ay += bf2f(v.y); az += bf2f(v.z); aw += bf2f(v.w);
            } else {
                float4 v = ff[(size_t)s * 16 + l];
                ax += v.x; ay += v.y; az += v.z; aw += v.w;
            }
        }
    }
    float inv = 1.0f / fmaxf((float)(end - beg), 1.0f);
    ((ushort4*)mean_b)[(size_t)n * 16 + l] =
        make_ushort4(f2bf(ax * inv), f2bf(ay * inv), f2bf(az * inv), f2bf(aw * inv));
}

// ---- dense via MFMA: 64 nodes/block, wave w -> node rows [16w,16w+16) --
// h = relu([mean|xin] @ [Wl;Wr]^T + bl).  LAYER 1: h -> bf16 ws.
// LAYER 2: h -> fp32 d_out + fused head out = h @ Wh^T + bh.
template <int LAYER>
__global__ __launch_bounds__(256) void dense_mfma(
    const unsigned short* __restrict__ mean_b,
    const float* __restrict__ xin_f,            // LAYER==1
    const unsigned short* __restrict__ xin_b,   // LAYER==2
    const unsigned short* __restrict__ wl_b,
    const float* __restrict__ bl,
    const unsigned short* __restrict__ wr_b,
    unsigned short* __restrict__ hout_b,        // LAYER==1
    float* __restrict__ hout_f,                 // LAYER==2
    const float* __restrict__ Wh, const float* __restrict__ bh,
    float* __restrict__ out)
{
    __shared__ __align__(16) char lds[18432 + 1024];
    unsigned short* sA = (unsigned short*)lds;          // mean tile [64][72] bf16
    unsigned short* sX = sA + 64 * 72;                  // xin  tile [64][72] bf16
    float* sH    = (float*)lds;                         // reused: h tile [64][68] f32
    float* spart = (float*)(lds + 18432);

    const int tid = threadIdx.x;
    const int n0  = blockIdx.x * 64;

    // ---- stage A operands into LDS (coalesced, bf16) ----
#pragma unroll
    for (int i = 0; i < 4; ++i) {
        int idx = tid + 256 * i;
        int row = idx >> 4, c4 = idx & 15;
        int n = n0 + row;
        ushort4 m4 = make_ushort4(0, 0, 0, 0);
        ushort4 x4 = make_ushort4(0, 0, 0, 0);
        if (n < N_NODES) {
            m4 = ((const ushort4*)mean_b)[(size_t)n * 16 + c4];
            if (LAYER == 1) {
                float4 xv = ((const float4*)xin_f)[(size_t)n * 16 + c4];
                x4 = make_ushort4(f2bf(xv.x), f2bf(xv.y), f2bf(xv.z), f2bf(xv.w));
            } else {
                x4 = ((const ushort4*)xin_b)[(size_t)n * 16 + c4];
            }
        }
        int b = row * 72 + c4 * 4;
        *(ushort4*)(sA + b) = m4;
        *(ushort4*)(sX + b) = x4;
    }
    __syncthreads();

    const int w = tid >> 6, l = tid & 63;
    const int rowl = l & 15, quad = l >> 4;

    // A frags: A[m=lane&15][k=quad*8+j], k-chunks 0-31 and 32-63
    const unsigned short* ab = sA + (w * 16 + rowl) * 72 + quad * 8;
    const unsigned short* xb = sX + (w * 16 + rowl) * 72 + quad * 8;
    bf16x8 am0 = *(const bf16x8*)(ab);
    bf16x8 am1 = *(const bf16x8*)(ab + 32);
    bf16x8 ax0 = *(const bf16x8*)(xb);
    bf16x8 ax1 = *(const bf16x8*)(xb + 32);
    __syncthreads();   // A/X consumed into regs; sH may overwrite

    f32x4 acc[4];
    float bj[4];
#pragma unroll
    for (int jt = 0; jt < 4; ++jt) {
        // B frags: B[k][n]=W[j][k], n=lane&15, k=quad*8+j  (row-major contiguous)
        const unsigned short* wlp = wl_b + (jt * 16 + rowl) * 64 + quad * 8;
        const unsigned short* wrp = wr_b + (jt * 16 + rowl) * 64 + quad * 8;
        bf16x8 b0 = *(const bf16x8*)(wlp);
        bf16x8 b1 = *(const bf16x8*)(wlp + 32);
        bf16x8 b2 = *(const bf16x8*)(wrp);
        bf16x8 b3 = *(const bf16x8*)(wrp + 32);
        f32x4 a = {0.f, 0.f, 0.f, 0.f};
        a = __builtin_amdgcn_mfma_f32_16x16x32_bf16(am0, b0, a, 0, 0, 0);
        a = __builtin_amdgcn_mfma_f32_16x16x32_bf16(am1, b1, a, 0, 0, 0);
        a = __builtin_amdgcn_mfma_f32_16x16x32_bf16(ax0, b2, a, 0, 0, 0);
        a = __builtin_amdgcn_mfma_f32_16x16x32_bf16(ax1, b3, a, 0, 0, 0);
        acc[jt] = a;
        bj[jt] = bl[jt * 16 + rowl];
    }

    // D: lane l, reg r -> node=(quad*4+r)+16w, col=jt*16+(lane&15)
#pragma unroll
    for (int jt = 0; jt < 4; ++jt) {
#pragma unroll
        for (int r = 0; r < 4; ++r) {
            int node = w * 16 + quad * 4 + r;
            float v = fmaxf(acc[jt][r] + bj[jt], 0.f);
            sH[node * 68 + jt * 16 + rowl] = v;
        }
    }
    __syncthreads();

    if (LAYER == 2) {
        int node = tid >> 2, q = tid & 3;
        float p = 0.f;
#pragma unroll
        for (int c = 0; c < 4; ++c) {
            float4 hv = *(const float4*)(sH + node * 68 + q * 16 + c * 4);
            float4 wv = ((const float4*)Wh)[q * 4 + c];
            p += hv.x * wv.x + hv.y * wv.y + hv.z * wv.z + hv.w * wv.w;
        }
        spart[tid] = p;
    }

    // ---- write h (coalesced from LDS) ----
#pragma unroll
    for (int i = 0; i < 4; ++i) {
        int idx = tid + 256 * i;
        int row = idx >> 4, c4 = idx & 15;
        int n = n0 + row;
        if (n < N_NODES) {
            const float* hp = sH + row * 68 + c4 * 4;
            if (LAYER == 1) {
                ((ushort4*)hout_b)[(size_t)n * 16 + c4] =
                    make_ushort4(f2bf(hp[0]), f2bf(hp[1]), f2bf(hp[2]), f2bf(hp[3]));
            } else {
                ((float4*)hout_f)[(size_t)n * 16 + c4] =
                    make_float4(hp[0], hp[1], hp[2], hp[3]);
            }
        }
    }

    if (LAYER == 2) {
        __syncthreads();
        if (tid < 64) {
            int n = n0 + tid;
            if (n < N_NODES)
                out[n] = bh[0] + spart[tid * 4 + 0] + spart[tid * 4 + 1] +
                         spart[tid * 4 + 2] + spart[tid * 4 + 3];
        }
    }
}

extern "C" void kernel_launch(void* const* d_in, const int* in_sizes, int n_in,
                              void* d_out, int out_size, void* d_ws, size_t ws_size,
                              hipStream_t stream) {
    const float* x   = (const float*)d_in[0];
    const int*   ei  = (const int*)d_in[1];
    const int*   src = ei;
    const int*   dst = ei + N_EDGES;
    const float* W1l = (const float*)d_in[2];
    const float* W1r = (const float*)d_in[3];
    const float* b1  = (const float*)d_in[4];
    const float* W2l = (const float*)d_in[5];
    const float* W2r = (const float*)d_in[6];
    const float* b2  = (const float*)d_in[7];
    const float* Wh  = (const float*)d_in[8];
    const float* bh  = (const float*)d_in[9];

    float* out   = (float*)d_out;        // [N]
    float* h_out = out + N_NODES;        // [N,64] final h2 (fp32)

    // ---- ws layout (ints) ----
    int* wsi      = (int*)d_ws;
    int* hist     = wsi;                             // NPAD
    int* rs       = wsi + NPAD;                      // N+1 used
    int* bsum     = wsi + 2 * NPAD;                  // 1024
    int* bscan    = wsi + 2 * NPAD + 1024;           // 1024
    unsigned short* wb = (unsigned short*)(wsi + 2 * NPAD + 2048);  // 16384 bf16
    int* csr_src  = wsi + 2 * NPAD + 2048 + 8192;    // N_EDGES
    unsigned short* mean_b = (unsigned short*)(csr_src + N_EDGES);  // N*64 bf16
    unsigned short* h1b    = mean_b + (size_t)N_NODES * D;          // N*64 bf16
    int* pos      = (int*)h1b;           // pos[e] dies before dense1 writes h1b

    unsigned short* w1l_b = wb;
    unsigned short* w1r_b = wb + 4096;
    unsigned short* w2l_b = wb + 8192;
    unsigned short* w2r_b = wb + 12288;

    const int EB  = (N_EDGES + 255) / 256;       // 5000
    const int NB  = (N_NODES + 255) / 256;       // 391
    const int GB  = (N_NODES * 16 + 255) / 256;  // 6250
    const int DB  = (N_NODES + 63) / 64;         // 1563

    hipMemsetAsync(d_ws, 0, (size_t)NPAD * sizeof(int), stream);

    // ---- CSR build + weight convert ----
    wcvt_kernel <<<64, 256, 0, stream>>>(W1l, W1r, W2l, W2r, wb);
    hist_kernel <<<EB, 256, 0, stream>>>(dst, hist, pos);
    scan1_kernel<<<NB, 256, 0, stream>>>(hist, rs, bsum);
    scan2_kernel<<<1, 512, 0, stream>>>(bsum, bscan, NB);
    scan3_kernel<<<NB, 256, 0, stream>>>(rs, bscan);
    fill_kernel <<<EB, 256, 0, stream>>>(src, dst, rs, pos, csr_src);

    // ---- layer 1 ----
    gather_kernel<false><<<GB, 256, 0, stream>>>(csr_src, rs, x, mean_b);
    dense_mfma<1><<<DB, 256, 0, stream>>>(
        mean_b, x, nullptr, w1l_b, b1, w1r_b, h1b, nullptr,
        nullptr, nullptr, nullptr);

    // ---- layer 2 ----
    gather_kernel<true><<<GB, 256, 0, stream>>>(csr_src, rs, h1b, mean_b);
    dense_mfma<2><<<DB, 256, 0, stream>>>(
        mean_b, nullptr, h1b, w2l_b, b2, w2r_b, nullptr, h_out,
        Wh, bh, out);
}